// Round 1
// baseline (204.960 us; speedup 1.0000x reference)
//
#include <hip/hip_runtime.h>
#include <hip/hip_bf16.h>

typedef __bf16 bf16x8 __attribute__((ext_vector_type(8)));
typedef float  f32x4  __attribute__((ext_vector_type(4)));
typedef int    i32x4  __attribute__((ext_vector_type(4)));

#define N_WORDS   8192
#define CHAR_LEN  16
#define WORD_DIM  300
#define CHAR_DIM  64
#define HID       128
#define G4        512      // 4*HID
#define INFO      556
#define KPAD      576      // 556 padded to 18*32
#define OUTD      512
#define WBL       32       // words per lstm block (2 M-tiles)
#define WBO       32       // words per out block
#define L2E       1.4426950408889634f

// tanh for the output kernel (unchanged path): 1 - 2*rcp(1+exp2(2x*log2e))
__device__ __forceinline__ float tanh_(float x) {
    return 1.0f - 2.0f * __builtin_amdgcn_rcpf(1.0f + __builtin_amdgcn_exp2f((2.0f * L2E) * x));
}

// K0 fused: blocks [0,256): preT ; blocks [256,...): Wpad + WhhB conversion.
// NEW: gate rows prescaled so MFMA output is exp2-ready:
//   rows i,f,o  -> * (-log2e)      => acc = -L2E*gate, sigma = rcp(1+2^acc)
//   rows g      -> * (-2*log2e)    => acc = -2*L2E*g,  tanh = (1-2^acc)/(1+2^acc)
__global__ void prep_kernel(const float* __restrict__ char_table,
                            const float* __restrict__ Wih_f, const float* __restrict__ bih_f,
                            const float* __restrict__ bhh_f,
                            const float* __restrict__ Wih_b, const float* __restrict__ bih_b,
                            const float* __restrict__ bhh_b,
                            const float* __restrict__ W_out,
                            const float* __restrict__ Whh_f, const float* __restrict__ Whh_b,
                            float* __restrict__ preT,
                            __bf16* __restrict__ Wpad, __bf16* __restrict__ WhhB) {
    __shared__ float x[CHAR_DIM];
    if (blockIdx.x < 256) {
        const int dir = blockIdx.x & 1;
        const int cid = blockIdx.x >> 1;
        const float* Wih = dir ? Wih_b : Wih_f;
        const float* b1  = dir ? bih_b : bih_f;
        const float* b2  = dir ? bhh_b : bhh_f;
        if (threadIdx.x < CHAR_DIM) x[threadIdx.x] = char_table[cid * CHAR_DIM + threadIdx.x];
        __syncthreads();
        for (int g = threadIdx.x; g < G4; g += 256) {
            const f32x4* w4 = (const f32x4*)(Wih + g * CHAR_DIM);
            const f32x4* x4 = (const f32x4*)x;
            float s = b1[g] + b2[g];
            #pragma unroll
            for (int d = 0; d < CHAR_DIM / 4; ++d) {
                f32x4 wv = w4[d], xv = x4[d];
                s += wv[0]*xv[0] + wv[1]*xv[1] + wv[2]*xv[2] + wv[3]*xv[3];
            }
            int tt = g >> 7, j = g & (HID - 1);
            float sc = (tt == 2) ? (-2.0f * L2E) : (-L2E);
            preT[(dir * 128 + cid) * G4 + j * 4 + tt] = s * sc;
        }
    } else {
        int idx = (blockIdx.x - 256) * 256 + threadIdx.x;
        if (idx < OUTD * KPAD) {
            int row = idx / KPAD, col = idx - row * KPAD;
            Wpad[idx] = (col < INFO) ? (__bf16)W_out[row * INFO + col] : (__bf16)0.0f;
        } else {
            int j = idx - OUTD * KPAD;
            if (j < 2 * G4 * HID) {
                const float* src = (j < G4 * HID) ? Whh_f : Whh_b;
                int k = (j < G4 * HID) ? j : j - G4 * HID;
                int gate = (k >> 14) & 3;   // row = k>>7, gate = row>>7
                float sc = (gate == 2) ? (-2.0f * L2E) : (-L2E);
                WhhB[j] = (__bf16)(src[k] * sc);
            }
        }
    }
}

// K2: persistent BiLSTM recurrence. Block: 32 words x 1 dir, 512 thr.
// Gate math rewritten: shared-denominator fractions, 8 trans/unit (was 10).
__global__ __launch_bounds__(512, 2) void lstm_kernel(
        const int*   __restrict__ char_ids,
        const float* __restrict__ preT,       // [2][128][128][4] fp32 gate-interleaved, prescaled
        const __bf16* __restrict__ WhhB,      // [2][512][128] bf16, prescaled
        __bf16* __restrict__ char_feat) {     // [8192][256] bf16
    const int dir = blockIdx.y;
    const int wb  = blockIdx.x * WBL;
    const __bf16* Whh = WhhB + dir * G4 * HID;
    const float* preD = preT + dir * 128 * G4;

    const int tid  = threadIdx.x;
    const int wave = tid >> 6;
    const int lane = tid & 63;
    const int col  = lane & 15;
    const int quad = lane >> 4;
    const int jbase = wave * 16;

    __shared__ __bf16 h_lds[2][WBL][136];
    __shared__ int    cidT[CHAR_LEN][WBL];

    {
        int w = tid >> 4, t = tid & 15;
        cidT[t][w] = char_ids[(wb + w) * CHAR_LEN + t] * (G4 * 4);
    }
    for (int i = tid; i < 2 * WBL * 136; i += 512) ((__bf16*)h_lds)[i] = (__bf16)0.0f;

    bf16x8 Bfrag[4][4];
    #pragma unroll
    for (int tt = 0; tt < 4; ++tt) {
        int row = tt * HID + jbase + col;
        #pragma unroll
        for (int ks = 0; ks < 4; ++ks)
            Bfrag[tt][ks] = *(const bf16x8*)(Whh + row * HID + ks * 32 + quad * 8);
    }

    const char* base_lane = (const char*)(preD + (jbase + col) * 4);

    float c[2][4] = {}, sumh[2][4] = {};

    __syncthreads();

    f32x4 nx[2][4];
    {
        const int tc0 = dir ? (CHAR_LEN - 1) : 0;
        #pragma unroll
        for (int mt = 0; mt < 2; ++mt) {
            i32x4 off = *(const i32x4*)(&cidT[tc0][mt * 16 + quad * 4]);
            #pragma unroll
            for (int r = 0; r < 4; ++r)
                nx[mt][r] = *(const f32x4*)(base_lane + off[r]);
        }
    }

    for (int t = 0; t < CHAR_LEN; ++t) {
        const __bf16 (*hc)[136] = h_lds[t & 1];
        __bf16 (*hn)[136] = h_lds[(t + 1) & 1];

        f32x4 acc[2][4];
        #pragma unroll
        for (int mt = 0; mt < 2; ++mt)
            #pragma unroll
            for (int tt = 0; tt < 4; ++tt)
                acc[mt][tt] = (f32x4){nx[mt][0][tt], nx[mt][1][tt], nx[mt][2][tt], nx[mt][3][tt]};

        __builtin_amdgcn_s_setprio(1);
        {
            bf16x8 A0 = *(const bf16x8*)(&hc[col][quad * 8]);
            bf16x8 A1 = *(const bf16x8*)(&hc[16 + col][quad * 8]);
            #pragma unroll
            for (int tt = 0; tt < 4; ++tt) {
                acc[0][tt] = __builtin_amdgcn_mfma_f32_16x16x32_bf16(A0, Bfrag[tt][0], acc[0][tt], 0, 0, 0);
                acc[1][tt] = __builtin_amdgcn_mfma_f32_16x16x32_bf16(A1, Bfrag[tt][0], acc[1][tt], 0, 0, 0);
            }
        }

        if (t + 1 < CHAR_LEN) {
            const int tc = dir ? (CHAR_LEN - 2 - t) : (t + 1);
            #pragma unroll
            for (int mt = 0; mt < 2; ++mt) {
                i32x4 off = *(const i32x4*)(&cidT[tc][mt * 16 + quad * 4]);
                #pragma unroll
                for (int r = 0; r < 4; ++r)
                    nx[mt][r] = *(const f32x4*)(base_lane + off[r]);
            }
        }

        #pragma unroll
        for (int ks = 1; ks < 4; ++ks) {
            bf16x8 A0 = *(const bf16x8*)(&hc[col][ks * 32 + quad * 8]);
            bf16x8 A1 = *(const bf16x8*)(&hc[16 + col][ks * 32 + quad * 8]);
            #pragma unroll
            for (int tt = 0; tt < 4; ++tt) {
                acc[0][tt] = __builtin_amdgcn_mfma_f32_16x16x32_bf16(A0, Bfrag[tt][ks], acc[0][tt], 0, 0, 0);
                acc[1][tt] = __builtin_amdgcn_mfma_f32_16x16x32_bf16(A1, Bfrag[tt][ks], acc[1][tt], 0, 0, 0);
            }
        }
        __builtin_amdgcn_s_setprio(0);

        // Gate math. acc_i/f/o = -L2E*gate, acc_g = -2*L2E*g (prescaled weights).
        //   sigma(x)         = rcp(1 + 2^acc)
        //   sigma(i)*tanh(g) = (1-u) * rcp((1+t)*(1+u)),  t=2^acc_i, u=2^acc_g
        //   sigma(o)*tanh(c) = (1-w) * rcp((1+v)*(1+w)),  v=2^acc_o, w=2^(-2*L2E*c)
        // Saturation: rcp(inf)=0 yields the correct limit everywhere; the only
        // NaN path ((1-u)=-inf times 0) is cut by clamping acc_g at +38.
        #pragma unroll
        for (int mt = 0; mt < 2; ++mt)
            #pragma unroll
            for (int r = 0; r < 4; ++r) {
                float ti = __builtin_amdgcn_exp2f(acc[mt][0][r]);
                float tf = __builtin_amdgcn_exp2f(acc[mt][1][r]);
                float tg = __builtin_amdgcn_exp2f(fminf(acc[mt][2][r], 38.0f));
                float to = __builtin_amdgcn_exp2f(acc[mt][3][r]);
                float sf = __builtin_amdgcn_rcpf(1.0f + tf);
                float ig = (1.0f - tg) * __builtin_amdgcn_rcpf((1.0f + ti) * (1.0f + tg));
                float cv = sf * c[mt][r] + ig;
                c[mt][r] = cv;
                float tc = __builtin_amdgcn_exp2f(cv * (-2.0f * L2E));
                float hv = (1.0f - tc) * __builtin_amdgcn_rcpf((1.0f + to) * (1.0f + tc));
                sumh[mt][r] += hv;
                hn[mt * 16 + quad * 4 + r][jbase + col] = (__bf16)hv;
            }
        __syncthreads();
    }

    #pragma unroll
    for (int mt = 0; mt < 2; ++mt)
        #pragma unroll
        for (int r = 0; r < 4; ++r)
            char_feat[(wb + mt * 16 + quad * 4 + r) * 256 + dir * HID + jbase + col]
                = (__bf16)sumh[mt][r];
}

// K3: 1024 thr (16 waves), M=32 words/block, wave owns M32 x N32 tile.
// Grid 256 = 1 block/CU -> 16 waves/CU hiding L2 B-load latency.
__global__ __launch_bounds__(1024, 4) void out_kernel(
        const int*   __restrict__ word_ids,
        const float* __restrict__ word_table,   // [50000][300] fp32
        const __bf16* __restrict__ char_feat,   // [8192][256] bf16
        const __bf16* __restrict__ Wpad,        // [512][576] bf16
        const float* __restrict__ b_out,        // [512] fp32
        float* __restrict__ out) {              // [8192][512] fp32
    const int wb  = blockIdx.x * WBO;
    const int tid = threadIdx.x;
    const int wave = tid >> 6, lane = tid & 63, col = lane & 15, quad = lane >> 4;
    const int nbase = wave * 32;   // 16 waves x 32 = 512 outputs

    __shared__ __bf16 feat[WBO][584];   // 1168B row stride, 16B aligned
    __shared__ int wid[WBO];
    if (tid < WBO) wid[tid] = word_ids[wb + tid];
    __syncthreads();
    // word part: 32 rows x 75 f32x4 chunks
    for (int idx = tid; idx < WBO * 75; idx += 1024) {
        int row = idx / 75, ch = idx - row * 75;
        f32x4 v = *(const f32x4*)(word_table + wid[row] * WORD_DIM + ch * 4);
        __bf16* d = &feat[row][ch * 4];
        d[0] = (__bf16)v[0]; d[1] = (__bf16)v[1]; d[2] = (__bf16)v[2]; d[3] = (__bf16)v[3];
    }
    // char part: 32 rows x 32 bf16x8 chunks = 1024 exactly
    {
        int row = tid >> 5, ch = tid & 31;
        bf16x8 v = *(const bf16x8*)(char_feat + (wb + row) * 256 + ch * 8);
        __bf16* d = &feat[row][WORD_DIM + ch * 8];
        #pragma unroll
        for (int e = 0; e < 8; ++e) d[e] = v[e];
    }
    // zero pad 556..583 : 32 x 28 = 896
    if (tid < WBO * 28) {
        int row = tid / 28, cc = tid - row * 28;
        feat[row][INFO + cc] = (__bf16)0.0f;
    }
    __syncthreads();

    f32x4 acc[2][2];   // [mt][nt]
    #pragma unroll
    for (int mt = 0; mt < 2; ++mt)
        #pragma unroll
        for (int nt = 0; nt < 2; ++nt) acc[mt][nt] = (f32x4){0.f, 0.f, 0.f, 0.f};

    const __bf16* Wp0 = Wpad + (nbase + col) * KPAD;
    const __bf16* Wp1 = Wpad + (nbase + 16 + col) * KPAD;

    #pragma unroll 2
    for (int kb = 0; kb < KPAD / 32; ++kb) {
        const int ko = kb * 32 + quad * 8;
        bf16x8 B0 = *(const bf16x8*)(Wp0 + ko);
        bf16x8 B1 = *(const bf16x8*)(Wp1 + ko);
        bf16x8 A0 = *(const bf16x8*)(&feat[col][ko]);
        bf16x8 A1 = *(const bf16x8*)(&feat[16 + col][ko]);
        acc[0][0] = __builtin_amdgcn_mfma_f32_16x16x32_bf16(A0, B0, acc[0][0], 0, 0, 0);
        acc[1][0] = __builtin_amdgcn_mfma_f32_16x16x32_bf16(A1, B0, acc[1][0], 0, 0, 0);
        acc[0][1] = __builtin_amdgcn_mfma_f32_16x16x32_bf16(A0, B1, acc[0][1], 0, 0, 0);
        acc[1][1] = __builtin_amdgcn_mfma_f32_16x16x32_bf16(A1, B1, acc[1][1], 0, 0, 0);
    }

    #pragma unroll
    for (int nt = 0; nt < 2; ++nt) {
        int n = nbase + nt * 16 + col;
        float bo = b_out[n];
        #pragma unroll
        for (int mt = 0; mt < 2; ++mt)
            #pragma unroll
            for (int r = 0; r < 4; ++r) {
                int word = wb + mt * 16 + quad * 4 + r;
                out[word * OUTD + n] = tanh_(acc[mt][nt][r] + bo);
            }
    }
}

extern "C" void kernel_launch(void* const* d_in, const int* in_sizes, int n_in,
                              void* d_out, int out_size, void* d_ws, size_t ws_size,
                              hipStream_t stream) {
    const int*   word_ids   = (const int*)d_in[0];
    const int*   char_ids   = (const int*)d_in[1];
    const float* word_table = (const float*)d_in[2];
    const float* char_table = (const float*)d_in[3];
    const float* Wih_f = (const float*)d_in[4];
    const float* Whh_f = (const float*)d_in[5];
    const float* bih_f = (const float*)d_in[6];
    const float* bhh_f = (const float*)d_in[7];
    const float* Wih_b = (const float*)d_in[8];
    const float* Whh_b = (const float*)d_in[9];
    const float* bih_b = (const float*)d_in[10];
    const float* bhh_b = (const float*)d_in[11];
    const float* W_out = (const float*)d_in[12];
    const float* b_out = (const float*)d_in[13];

    char* ws = (char*)d_ws;
    float*  preT      = (float*)ws;                         // 512 KB
    __bf16* WhhB      = (__bf16*)(ws + 524288);             // 256 KB
    __bf16* Wpad      = (__bf16*)(ws + 524288 + 262144);    // 576 KB
    __bf16* char_feat = (__bf16*)(ws + 524288 + 262144 + 589824);  // 4 MB

    prep_kernel<<<256 + (OUTD * KPAD + 2 * G4 * HID + 255) / 256, 256, 0, stream>>>(
        char_table, Wih_f, bih_f, bhh_f, Wih_b, bih_b, bhh_b,
        W_out, Whh_f, Whh_b, preT, Wpad, WhhB);
    lstm_kernel<<<dim3(N_WORDS / WBL, 2), 512, 0, stream>>>(char_ids, preT, WhhB, char_feat);
    out_kernel<<<N_WORDS / WBO, 1024, 0, stream>>>(word_ids, word_table, char_feat, Wpad, b_out,
                                                   (float*)d_out);
}

// Round 2
// 202.364 us; speedup vs baseline: 1.0128x; 1.0128x over previous
//
#include <hip/hip_runtime.h>
#include <hip/hip_bf16.h>

typedef __bf16 bf16x8 __attribute__((ext_vector_type(8)));
typedef float  f32x4  __attribute__((ext_vector_type(4)));
typedef int    i32x4  __attribute__((ext_vector_type(4)));

#define N_WORDS   8192
#define CHAR_LEN  16
#define WORD_DIM  300
#define CHAR_DIM  64
#define HID       128
#define G4        512      // 4*HID
#define INFO      556
#define KPAD      576      // 556 padded to 18*32
#define OUTD      512
#define WBL       32       // words per lstm block (2 pipelined groups of 16)
#define WBO       32       // words per out block
#define L2E       1.4426950408889634f

// tanh for the output kernel: 1 - 2*rcp(1+exp2(2x*log2e))
__device__ __forceinline__ float tanh_(float x) {
    return 1.0f - 2.0f * __builtin_amdgcn_rcpf(1.0f + __builtin_amdgcn_exp2f((2.0f * L2E) * x));
}

// K0 fused: blocks [0,256): preT ; blocks [256,...): Wpad + WhhB conversion.
// Gate rows prescaled so MFMA output is exp2-ready:
//   rows i,f,o  -> * (-log2e)      => acc = -L2E*gate, sigma = rcp(1+2^acc)
//   rows g      -> * (-2*log2e)    => acc = -2*L2E*g,  tanh = (1-2^acc)/(1+2^acc)
__global__ void prep_kernel(const float* __restrict__ char_table,
                            const float* __restrict__ Wih_f, const float* __restrict__ bih_f,
                            const float* __restrict__ bhh_f,
                            const float* __restrict__ Wih_b, const float* __restrict__ bih_b,
                            const float* __restrict__ bhh_b,
                            const float* __restrict__ W_out,
                            const float* __restrict__ Whh_f, const float* __restrict__ Whh_b,
                            float* __restrict__ preT,
                            __bf16* __restrict__ Wpad, __bf16* __restrict__ WhhB) {
    __shared__ float x[CHAR_DIM];
    if (blockIdx.x < 256) {
        const int dir = blockIdx.x & 1;
        const int cid = blockIdx.x >> 1;
        const float* Wih = dir ? Wih_b : Wih_f;
        const float* b1  = dir ? bih_b : bih_f;
        const float* b2  = dir ? bhh_b : bhh_f;
        if (threadIdx.x < CHAR_DIM) x[threadIdx.x] = char_table[cid * CHAR_DIM + threadIdx.x];
        __syncthreads();
        for (int g = threadIdx.x; g < G4; g += 256) {
            const f32x4* w4 = (const f32x4*)(Wih + g * CHAR_DIM);
            const f32x4* x4 = (const f32x4*)x;
            float s = b1[g] + b2[g];
            #pragma unroll
            for (int d = 0; d < CHAR_DIM / 4; ++d) {
                f32x4 wv = w4[d], xv = x4[d];
                s += wv[0]*xv[0] + wv[1]*xv[1] + wv[2]*xv[2] + wv[3]*xv[3];
            }
            int tt = g >> 7, j = g & (HID - 1);
            float sc = (tt == 2) ? (-2.0f * L2E) : (-L2E);
            preT[(dir * 128 + cid) * G4 + j * 4 + tt] = s * sc;
        }
    } else {
        int idx = (blockIdx.x - 256) * 256 + threadIdx.x;
        if (idx < OUTD * KPAD) {
            int row = idx / KPAD, col = idx - row * KPAD;
            Wpad[idx] = (col < INFO) ? (__bf16)W_out[row * INFO + col] : (__bf16)0.0f;
        } else {
            int j = idx - OUTD * KPAD;
            if (j < 2 * G4 * HID) {
                const float* src = (j < G4 * HID) ? Whh_f : Whh_b;
                int k = (j < G4 * HID) ? j : j - G4 * HID;
                int gate = (k >> 14) & 3;   // row = k>>7, gate = row>>7
                float sc = (gate == 2) ? (-2.0f * L2E) : (-L2E);
                WhhB[j] = (__bf16)(src[k] * sc);
            }
        }
    }
}

// K2: persistent BiLSTM recurrence, 2-group software pipeline.
// Block: 32 words x 1 dir, 512 thr = 8 waves. Groups g0 = words 0-15, g1 = 16-31.
// Interval structure (31 intervals): MFMA(gX, t) runs concurrently with the
// data-independent gates(gY, t-1) -> trans chains fill the MFMA shadow.
__global__ __launch_bounds__(512, 2) void lstm_kernel(
        const int*   __restrict__ char_ids,
        const float* __restrict__ preT,       // [2][128][128][4] fp32 gate-interleaved, prescaled
        const __bf16* __restrict__ WhhB,      // [2][512][128] bf16, prescaled
        __bf16* __restrict__ char_feat) {     // [8192][256] bf16
    const int dir = blockIdx.y;
    const int wb  = blockIdx.x * WBL;
    const __bf16* Whh = WhhB + dir * G4 * HID;
    const float* preD = preT + dir * 128 * G4;

    const int tid  = threadIdx.x;
    const int wave = tid >> 6;
    const int lane = tid & 63;
    const int col  = lane & 15;
    const int quad = lane >> 4;
    const int jbase = wave * 16;

    __shared__ __bf16 h_lds[2][WBL][136];   // [buf][word][j], rows 0-15 = g0, 16-31 = g1
    __shared__ int    cidT[CHAR_LEN][WBL];

    {
        int w = tid >> 4, t = tid & 15;
        cidT[t][w] = char_ids[(wb + w) * CHAR_LEN + t] * (G4 * 4);
    }

    bf16x8 Bfrag[4][4];
    #pragma unroll
    for (int tt = 0; tt < 4; ++tt) {
        int row = tt * HID + jbase + col;
        #pragma unroll
        for (int ks = 0; ks < 4; ++ks)
            Bfrag[tt][ks] = *(const bf16x8*)(Whh + row * HID + ks * 32 + quad * 8);
    }

    const char* base_lane = (const char*)(preD + (jbase + col) * 4);

    f32x4 nx0[4], nx1[4], acc0[4], acc1[4];
    float c0[4] = {}, c1[4] = {}, s0[4] = {}, s1[4] = {};

    // gather pre-activations for group g, step t (4 words per lane, 16B each)
    auto pref = [&](f32x4* nx, int g, int t) {
        const int tc = dir ? (CHAR_LEN - 1 - t) : t;
        i32x4 off = *(const i32x4*)(&cidT[tc][g * 16 + quad * 4]);
        #pragma unroll
        for (int r = 0; r < 4; ++r)
            nx[r] = *(const f32x4*)(base_lane + off[r]);
    };
    // acc[tt][r] = pre-activation for (word quad*4+r of group, gate tt, j=jbase+col)
    auto accinit = [&](f32x4* acc, const f32x4* nx) {
        #pragma unroll
        for (int tt = 0; tt < 4; ++tt)
            acc[tt] = (f32x4){nx[0][tt], nx[1][tt], nx[2][tt], nx[3][tt]};
    };
    // acc += Whh . h_g(t-1)  (h from LDS buffer `buf`, rows g*16..g*16+15)
    auto mfmag = [&](f32x4* acc, int g, int buf) {
        const __bf16 (*hc)[136] = h_lds[buf];
        #pragma unroll
        for (int ks = 0; ks < 4; ++ks) {
            bf16x8 A = *(const bf16x8*)(&hc[g * 16 + col][ks * 32 + quad * 8]);
            #pragma unroll
            for (int tt = 0; tt < 4; ++tt)
                acc[tt] = __builtin_amdgcn_mfma_f32_16x16x32_bf16(A, Bfrag[tt][ks], acc[tt], 0, 0, 0);
        }
    };
    // Gate math. acc_i/f/o = -L2E*gate, acc_g = -2*L2E*g (prescaled weights).
    //   sigma(x)         = rcp(1 + 2^acc)
    //   sigma(i)*tanh(g) = (1-u) * rcp((1+t)*(1+u))
    //   sigma(o)*tanh(c) = (1-w) * rcp((1+v)*(1+w)),  w=2^(-2*L2E*c)
    // rcp(inf)=0 gives the correct limit; NaN path cut by clamping acc_g at +38.
    auto gates = [&](f32x4* acc, float* c, float* sh, int g, int buf, bool wr) {
        __bf16 (*hn)[136] = h_lds[buf];
        #pragma unroll
        for (int r = 0; r < 4; ++r) {
            float ti = __builtin_amdgcn_exp2f(acc[0][r]);
            float tf = __builtin_amdgcn_exp2f(acc[1][r]);
            float tg = __builtin_amdgcn_exp2f(fminf(acc[2][r], 38.0f));
            float to = __builtin_amdgcn_exp2f(acc[3][r]);
            float sf = __builtin_amdgcn_rcpf(1.0f + tf);
            float ig = (1.0f - tg) * __builtin_amdgcn_rcpf((1.0f + ti) * (1.0f + tg));
            float cv = sf * c[r] + ig;
            c[r] = cv;
            float tc2 = __builtin_amdgcn_exp2f(cv * (-2.0f * L2E));
            float hv = (1.0f - tc2) * __builtin_amdgcn_rcpf((1.0f + to) * (1.0f + tc2));
            sh[r] += hv;
            if (wr) hn[g * 16 + quad * 4 + r][jbase + col] = (__bf16)hv;
        }
    };

    __syncthreads();   // cidT visible

    // Prologue: t=0 has h(-1)=0 -> no MFMA for either group.
    pref(nx0, 0, 0);
    pref(nx1, 1, 0);
    accinit(acc0, nx0);
    pref(nx0, 0, 1);           // nx0(1), consumed at interval t=1 even
    accinit(acc1, nx1);
    gates(acc0, c0, s0, 0, 0, true);     // h_g0(0) -> buf 0
    __syncthreads();

    for (int t = 1; t < CHAR_LEN; ++t) {
        // even interval 2t: MFMA_g0(t) || gates_g1(t-1)
        accinit(acc0, nx0);
        mfmag(acc0, 0, (t - 1) & 1);             // reads h_g0(t-1)
        pref(nx1, 1, t);                          // nx1(t) for next interval
        gates(acc1, c1, s1, 1, (t - 1) & 1, true);   // h_g1(t-1) -> buf (t-1)&1
        __syncthreads();
        // odd interval 2t+1: MFMA_g1(t) || gates_g0(t)
        accinit(acc1, nx1);
        mfmag(acc1, 1, (t - 1) & 1);             // reads h_g1(t-1)
        if (t + 1 < CHAR_LEN) pref(nx0, 0, t + 1);
        gates(acc0, c0, s0, 0, t & 1, t + 1 < CHAR_LEN);  // h_g0(t) -> buf t&1
        __syncthreads();
    }
    // Epilogue: gates_g1(15), no h write needed.
    gates(acc1, c1, s1, 1, 0, false);

    #pragma unroll
    for (int r = 0; r < 4; ++r) {
        char_feat[(wb + quad * 4 + r) * 256 + dir * HID + jbase + col]      = (__bf16)s0[r];
        char_feat[(wb + 16 + quad * 4 + r) * 256 + dir * HID + jbase + col] = (__bf16)s1[r];
    }
}

// K3: 1024 thr (16 waves), M=32 words/block, wave owns M32 x N32 tile.
__global__ __launch_bounds__(1024, 4) void out_kernel(
        const int*   __restrict__ word_ids,
        const float* __restrict__ word_table,   // [50000][300] fp32
        const __bf16* __restrict__ char_feat,   // [8192][256] bf16
        const __bf16* __restrict__ Wpad,        // [512][576] bf16
        const float* __restrict__ b_out,        // [512] fp32
        float* __restrict__ out) {              // [8192][512] fp32
    const int wb  = blockIdx.x * WBO;
    const int tid = threadIdx.x;
    const int wave = tid >> 6, lane = tid & 63, col = lane & 15, quad = lane >> 4;
    const int nbase = wave * 32;   // 16 waves x 32 = 512 outputs

    __shared__ __bf16 feat[WBO][584];   // 1168B row stride, 16B aligned
    __shared__ int wid[WBO];
    if (tid < WBO) wid[tid] = word_ids[wb + tid];
    __syncthreads();
    // word part: 32 rows x 75 f32x4 chunks
    for (int idx = tid; idx < WBO * 75; idx += 1024) {
        int row = idx / 75, ch = idx - row * 75;
        f32x4 v = *(const f32x4*)(word_table + wid[row] * WORD_DIM + ch * 4);
        __bf16* d = &feat[row][ch * 4];
        d[0] = (__bf16)v[0]; d[1] = (__bf16)v[1]; d[2] = (__bf16)v[2]; d[3] = (__bf16)v[3];
    }
    // char part: 32 rows x 32 bf16x8 chunks = 1024 exactly
    {
        int row = tid >> 5, ch = tid & 31;
        bf16x8 v = *(const bf16x8*)(char_feat + (wb + row) * 256 + ch * 8);
        __bf16* d = &feat[row][WORD_DIM + ch * 8];
        #pragma unroll
        for (int e = 0; e < 8; ++e) d[e] = v[e];
    }
    // zero pad 556..583 : 32 x 28 = 896
    if (tid < WBO * 28) {
        int row = tid / 28, cc = tid - row * 28;
        feat[row][INFO + cc] = (__bf16)0.0f;
    }
    __syncthreads();

    f32x4 acc[2][2];   // [mt][nt]
    #pragma unroll
    for (int mt = 0; mt < 2; ++mt)
        #pragma unroll
        for (int nt = 0; nt < 2; ++nt) acc[mt][nt] = (f32x4){0.f, 0.f, 0.f, 0.f};

    const __bf16* Wp0 = Wpad + (nbase + col) * KPAD;
    const __bf16* Wp1 = Wpad + (nbase + 16 + col) * KPAD;

    #pragma unroll 2
    for (int kb = 0; kb < KPAD / 32; ++kb) {
        const int ko = kb * 32 + quad * 8;
        bf16x8 B0 = *(const bf16x8*)(Wp0 + ko);
        bf16x8 B1 = *(const bf16x8*)(Wp1 + ko);
        bf16x8 A0 = *(const bf16x8*)(&feat[col][ko]);
        bf16x8 A1 = *(const bf16x8*)(&feat[16 + col][ko]);
        acc[0][0] = __builtin_amdgcn_mfma_f32_16x16x32_bf16(A0, B0, acc[0][0], 0, 0, 0);
        acc[1][0] = __builtin_amdgcn_mfma_f32_16x16x32_bf16(A1, B0, acc[1][0], 0, 0, 0);
        acc[0][1] = __builtin_amdgcn_mfma_f32_16x16x32_bf16(A0, B1, acc[0][1], 0, 0, 0);
        acc[1][1] = __builtin_amdgcn_mfma_f32_16x16x32_bf16(A1, B1, acc[1][1], 0, 0, 0);
    }

    #pragma unroll
    for (int nt = 0; nt < 2; ++nt) {
        int n = nbase + nt * 16 + col;
        float bo = b_out[n];
        #pragma unroll
        for (int mt = 0; mt < 2; ++mt)
            #pragma unroll
            for (int r = 0; r < 4; ++r) {
                int word = wb + mt * 16 + quad * 4 + r;
                out[word * OUTD + n] = tanh_(acc[mt][nt][r] + bo);
            }
    }
}

extern "C" void kernel_launch(void* const* d_in, const int* in_sizes, int n_in,
                              void* d_out, int out_size, void* d_ws, size_t ws_size,
                              hipStream_t stream) {
    const int*   word_ids   = (const int*)d_in[0];
    const int*   char_ids   = (const int*)d_in[1];
    const float* word_table = (const float*)d_in[2];
    const float* char_table = (const float*)d_in[3];
    const float* Wih_f = (const float*)d_in[4];
    const float* Whh_f = (const float*)d_in[5];
    const float* bih_f = (const float*)d_in[6];
    const float* bhh_f = (const float*)d_in[7];
    const float* Wih_b = (const float*)d_in[8];
    const float* Whh_b = (const float*)d_in[9];
    const float* bih_b = (const float*)d_in[10];
    const float* bhh_b = (const float*)d_in[11];
    const float* W_out = (const float*)d_in[12];
    const float* b_out = (const float*)d_in[13];

    char* ws = (char*)d_ws;
    float*  preT      = (float*)ws;                         // 512 KB
    __bf16* WhhB      = (__bf16*)(ws + 524288);             // 256 KB
    __bf16* Wpad      = (__bf16*)(ws + 524288 + 262144);    // 576 KB
    __bf16* char_feat = (__bf16*)(ws + 524288 + 262144 + 589824);  // 4 MB

    prep_kernel<<<256 + (OUTD * KPAD + 2 * G4 * HID + 255) / 256, 256, 0, stream>>>(
        char_table, Wih_f, bih_f, bhh_f, Wih_b, bih_b, bhh_b,
        W_out, Whh_f, Whh_b, preT, Wpad, WhhB);
    lstm_kernel<<<dim3(N_WORDS / WBL, 2), 512, 0, stream>>>(char_ids, preT, WhhB, char_feat);
    out_kernel<<<N_WORDS / WBO, 1024, 0, stream>>>(word_ids, word_table, char_feat, Wpad, b_out,
                                                   (float*)d_out);
}

// Round 4
// 198.088 us; speedup vs baseline: 1.0347x; 1.0216x over previous
//
#include <hip/hip_runtime.h>
#include <hip/hip_bf16.h>

typedef __bf16 bf16x8 __attribute__((ext_vector_type(8)));
typedef float  f32x4  __attribute__((ext_vector_type(4)));
typedef int    i32x4  __attribute__((ext_vector_type(4)));

#define N_WORDS   8192
#define CHAR_LEN  16
#define WORD_DIM  300
#define CHAR_DIM  64
#define HID       128
#define G4        512      // 4*HID
#define INFO      556
#define KPAD      576      // 556 padded to 18*32
#define OUTD      512
#define WBL       16       // words per lstm block (one M16 tile)
#define WBO       32       // words per out block
#define L2E       1.4426950408889634f

// tanh for the output kernel: 1 - 2*rcp(1+exp2(2x*log2e))
__device__ __forceinline__ float tanh_(float x) {
    return 1.0f - 2.0f * __builtin_amdgcn_rcpf(1.0f + __builtin_amdgcn_exp2f((2.0f * L2E) * x));
}

// K0 fused: blocks [0,256): preT ; blocks [256,...): Wpad + WhhB conversion.
// Gate rows prescaled so MFMA output is exp2-ready:
//   rows i,f,o  -> * (-log2e)      => acc = -L2E*gate, sigma = rcp(1+2^acc)
//   rows g      -> * (-2*log2e)    => acc = -2*L2E*g,  tanh = (1-2^acc)/(1+2^acc)
__global__ void prep_kernel(const float* __restrict__ char_table,
                            const float* __restrict__ Wih_f, const float* __restrict__ bih_f,
                            const float* __restrict__ bhh_f,
                            const float* __restrict__ Wih_b, const float* __restrict__ bih_b,
                            const float* __restrict__ bhh_b,
                            const float* __restrict__ W_out,
                            const float* __restrict__ Whh_f, const float* __restrict__ Whh_b,
                            float* __restrict__ preT,
                            __bf16* __restrict__ Wpad, __bf16* __restrict__ WhhB) {
    __shared__ float x[CHAR_DIM];
    if (blockIdx.x < 256) {
        const int dir = blockIdx.x & 1;
        const int cid = blockIdx.x >> 1;
        const float* Wih = dir ? Wih_b : Wih_f;
        const float* b1  = dir ? bih_b : bih_f;
        const float* b2  = dir ? bhh_b : bhh_f;
        if (threadIdx.x < CHAR_DIM) x[threadIdx.x] = char_table[cid * CHAR_DIM + threadIdx.x];
        __syncthreads();
        for (int g = threadIdx.x; g < G4; g += 256) {
            const f32x4* w4 = (const f32x4*)(Wih + g * CHAR_DIM);
            const f32x4* x4 = (const f32x4*)x;
            float s = b1[g] + b2[g];
            #pragma unroll
            for (int d = 0; d < CHAR_DIM / 4; ++d) {
                f32x4 wv = w4[d], xv = x4[d];
                s += wv[0]*xv[0] + wv[1]*xv[1] + wv[2]*xv[2] + wv[3]*xv[3];
            }
            int tt = g >> 7, j = g & (HID - 1);
            float sc = (tt == 2) ? (-2.0f * L2E) : (-L2E);
            preT[(dir * 128 + cid) * G4 + j * 4 + tt] = s * sc;
        }
    } else {
        int idx = (blockIdx.x - 256) * 256 + threadIdx.x;
        if (idx < OUTD * KPAD) {
            int row = idx / KPAD, col = idx - row * KPAD;
            Wpad[idx] = (col < INFO) ? (__bf16)W_out[row * INFO + col] : (__bf16)0.0f;
        } else {
            int j = idx - OUTD * KPAD;
            if (j < 2 * G4 * HID) {
                const float* src = (j < G4 * HID) ? Whh_f : Whh_b;
                int k = (j < G4 * HID) ? j : j - G4 * HID;
                int gate = (k >> 14) & 3;   // row = k>>7, gate = row>>7
                float sc = (gate == 2) ? (-2.0f * L2E) : (-L2E);
                WhhB[j] = (__bf16)(src[k] * sc);
            }
        }
    }
}

// K2: persistent BiLSTM recurrence.
// Block: 16 words x 1 dir, 512 thr = 8 waves; wave = 16-j slice x M16 words.
// Halved per-wave register state (acc 16, nx 16) so combined VGPR+AGPR <= 128
// -> 4 waves/SIMD (2 blocks/CU) instead of 2 waves/SIMD. One barrier/step.
__global__ __launch_bounds__(512, 4) void lstm_kernel(
        const int*   __restrict__ char_ids,
        const float* __restrict__ preT,       // [2][128][128][4] fp32 gate-interleaved, prescaled
        const __bf16* __restrict__ WhhB,      // [2][512][128] bf16, prescaled
        __bf16* __restrict__ char_feat) {     // [8192][256] bf16
    const int dir = blockIdx.y;
    const int wb  = blockIdx.x * WBL;
    const __bf16* Whh = WhhB + dir * G4 * HID;
    const float* preD = preT + dir * 128 * G4;

    const int tid  = threadIdx.x;
    const int wave = tid >> 6;
    const int lane = tid & 63;
    const int col  = lane & 15;
    const int quad = lane >> 4;
    const int jbase = wave * 16;

    __shared__ __bf16 h_lds[2][WBL][136];   // [buf][word][j]
    __shared__ int    cidT[CHAR_LEN][WBL];

    if (tid < CHAR_LEN * WBL) {
        int w = tid >> 4, t = tid & 15;
        cidT[t][w] = char_ids[(wb + w) * CHAR_LEN + t] * (G4 * 4);
    }

    bf16x8 Bfrag[4][4];
    #pragma unroll
    for (int tt = 0; tt < 4; ++tt) {
        int row = tt * HID + jbase + col;
        #pragma unroll
        for (int ks = 0; ks < 4; ++ks)
            Bfrag[tt][ks] = *(const bf16x8*)(Whh + row * HID + ks * 32 + quad * 8);
    }

    const char* base_lane = (const char*)(preD + (jbase + col) * 4);

    f32x4 nx[4], acc[4];
    float c[4] = {}, s[4] = {};

    // gather pre-activations for step t (4 words per lane, 16B each)
    auto pref = [&](int t) {
        const int tc = dir ? (CHAR_LEN - 1 - t) : t;
        i32x4 off = *(const i32x4*)(&cidT[tc][quad * 4]);
        #pragma unroll
        for (int r = 0; r < 4; ++r)
            nx[r] = *(const f32x4*)(base_lane + off[r]);
    };
    auto accinit = [&]() {
        #pragma unroll
        for (int tt = 0; tt < 4; ++tt)
            acc[tt] = (f32x4){nx[0][tt], nx[1][tt], nx[2][tt], nx[3][tt]};
    };
    // acc += Whh . h(t-1)  (h from LDS buffer `buf`)
    auto mfmag = [&](int buf) {
        const __bf16 (*hc)[136] = h_lds[buf];
        #pragma unroll
        for (int ks = 0; ks < 4; ++ks) {
            bf16x8 A = *(const bf16x8*)(&hc[col][ks * 32 + quad * 8]);
            #pragma unroll
            for (int tt = 0; tt < 4; ++tt)
                acc[tt] = __builtin_amdgcn_mfma_f32_16x16x32_bf16(A, Bfrag[tt][ks], acc[tt], 0, 0, 0);
        }
    };
    // Gate math. acc_i/f/o = -L2E*gate, acc_g = -2*L2E*g (prescaled weights).
    //   sigma(x)         = rcp(1 + 2^acc)
    //   sigma(i)*tanh(g) = (1-u) * rcp((1+t)*(1+u))
    //   sigma(o)*tanh(c) = (1-w) * rcp((1+v)*(1+w)),  w=2^(-2*L2E*c)
    // rcp(inf)=0 gives the correct limit; NaN path cut by clamping acc_g at +38.
    auto gates = [&](int buf, bool wr) {
        __bf16 (*hn)[136] = h_lds[buf];
        #pragma unroll
        for (int r = 0; r < 4; ++r) {
            float ti = __builtin_amdgcn_exp2f(acc[0][r]);
            float tf = __builtin_amdgcn_exp2f(acc[1][r]);
            float tg = __builtin_amdgcn_exp2f(fminf(acc[2][r], 38.0f));
            float to = __builtin_amdgcn_exp2f(acc[3][r]);
            float sf = __builtin_amdgcn_rcpf(1.0f + tf);
            float ig = (1.0f - tg) * __builtin_amdgcn_rcpf((1.0f + ti) * (1.0f + tg));
            float cv = sf * c[r] + ig;
            c[r] = cv;
            float tc2 = __builtin_amdgcn_exp2f(cv * (-2.0f * L2E));
            float hv = (1.0f - tc2) * __builtin_amdgcn_rcpf((1.0f + to) * (1.0f + tc2));
            s[r] += hv;
            if (wr) hn[quad * 4 + r][jbase + col] = (__bf16)hv;
        }
    };

    __syncthreads();   // cidT visible

    // t = 0: h(-1) = 0 -> no MFMA.
    pref(0);
    accinit();
    pref(1);
    gates(0, true);            // h(0) -> buf 0
    __syncthreads();

    // t = 1..14, 2x unrolled for static buffer indices.
    #pragma unroll 1
    for (int tb = 1; tb < CHAR_LEN - 1; tb += 2) {
        // odd t: read buf 0, write buf 1
        accinit();
        pref(tb + 1);
        mfmag(0);
        gates(1, true);
        __syncthreads();
        // even t: read buf 1, write buf 0
        accinit();
        pref(tb + 2);
        mfmag(1);
        gates(0, true);
        __syncthreads();
    }

    // t = 15: read buf 0, no write.
    accinit();
    mfmag(0);
    gates(1, false);

    #pragma unroll
    for (int r = 0; r < 4; ++r)
        char_feat[(wb + quad * 4 + r) * 256 + dir * HID + jbase + col] = (__bf16)s[r];
}

// K3: 1024 thr (16 waves), M=32 words/block, wave owns M32 x N32 tile.
__global__ __launch_bounds__(1024, 4) void out_kernel(
        const int*   __restrict__ word_ids,
        const float* __restrict__ word_table,   // [50000][300] fp32
        const __bf16* __restrict__ char_feat,   // [8192][256] bf16
        const __bf16* __restrict__ Wpad,        // [512][576] bf16
        const float* __restrict__ b_out,        // [512] fp32
        float* __restrict__ out) {              // [8192][512] fp32
    const int wb  = blockIdx.x * WBO;
    const int tid = threadIdx.x;
    const int wave = tid >> 6, lane = tid & 63, col = lane & 15, quad = lane >> 4;
    const int nbase = wave * 32;   // 16 waves x 32 = 512 outputs

    __shared__ __bf16 feat[WBO][584];   // 1168B row stride, 16B aligned
    __shared__ int wid[WBO];
    if (tid < WBO) wid[tid] = word_ids[wb + tid];
    __syncthreads();
    // word part: 32 rows x 75 f32x4 chunks
    for (int idx = tid; idx < WBO * 75; idx += 1024) {
        int row = idx / 75, ch = idx - row * 75;
        f32x4 v = *(const f32x4*)(word_table + wid[row] * WORD_DIM + ch * 4);
        __bf16* d = &feat[row][ch * 4];
        d[0] = (__bf16)v[0]; d[1] = (__bf16)v[1]; d[2] = (__bf16)v[2]; d[3] = (__bf16)v[3];
    }
    // char part: 32 rows x 32 bf16x8 chunks = 1024 exactly
    {
        int row = tid >> 5, ch = tid & 31;
        bf16x8 v = *(const bf16x8*)(char_feat + (wb + row) * 256 + ch * 8);
        __bf16* d = &feat[row][WORD_DIM + ch * 8];
        #pragma unroll
        for (int e = 0; e < 8; ++e) d[e] = v[e];
    }
    // zero pad 556..583 : 32 x 28 = 896
    if (tid < WBO * 28) {
        int row = tid / 28, cc = tid - row * 28;
        feat[row][INFO + cc] = (__bf16)0.0f;
    }
    __syncthreads();

    f32x4 acc[2][2];   // [mt][nt]
    #pragma unroll
    for (int mt = 0; mt < 2; ++mt)
        #pragma unroll
        for (int nt = 0; nt < 2; ++nt) acc[mt][nt] = (f32x4){0.f, 0.f, 0.f, 0.f};

    const __bf16* Wp0 = Wpad + (nbase + col) * KPAD;
    const __bf16* Wp1 = Wpad + (nbase + 16 + col) * KPAD;

    #pragma unroll 2
    for (int kb = 0; kb < KPAD / 32; ++kb) {
        const int ko = kb * 32 + quad * 8;
        bf16x8 B0 = *(const bf16x8*)(Wp0 + ko);
        bf16x8 B1 = *(const bf16x8*)(Wp1 + ko);
        bf16x8 A0 = *(const bf16x8*)(&feat[col][ko]);
        bf16x8 A1 = *(const bf16x8*)(&feat[16 + col][ko]);
        acc[0][0] = __builtin_amdgcn_mfma_f32_16x16x32_bf16(A0, B0, acc[0][0], 0, 0, 0);
        acc[1][0] = __builtin_amdgcn_mfma_f32_16x16x32_bf16(A1, B0, acc[1][0], 0, 0, 0);
        acc[0][1] = __builtin_amdgcn_mfma_f32_16x16x32_bf16(A0, B1, acc[0][1], 0, 0, 0);
        acc[1][1] = __builtin_amdgcn_mfma_f32_16x16x32_bf16(A1, B1, acc[1][1], 0, 0, 0);
    }

    #pragma unroll
    for (int nt = 0; nt < 2; ++nt) {
        int n = nbase + nt * 16 + col;
        float bo = b_out[n];
        #pragma unroll
        for (int mt = 0; mt < 2; ++mt)
            #pragma unroll
            for (int r = 0; r < 4; ++r) {
                int word = wb + mt * 16 + quad * 4 + r;
                out[word * OUTD + n] = tanh_(acc[mt][nt][r] + bo);
            }
    }
}

extern "C" void kernel_launch(void* const* d_in, const int* in_sizes, int n_in,
                              void* d_out, int out_size, void* d_ws, size_t ws_size,
                              hipStream_t stream) {
    const int*   word_ids   = (const int*)d_in[0];
    const int*   char_ids   = (const int*)d_in[1];
    const float* word_table = (const float*)d_in[2];
    const float* char_table = (const float*)d_in[3];
    const float* Wih_f = (const float*)d_in[4];
    const float* Whh_f = (const float*)d_in[5];
    const float* bih_f = (const float*)d_in[6];
    const float* bhh_f = (const float*)d_in[7];
    const float* Wih_b = (const float*)d_in[8];
    const float* Whh_b = (const float*)d_in[9];
    const float* bih_b = (const float*)d_in[10];
    const float* bhh_b = (const float*)d_in[11];
    const float* W_out = (const float*)d_in[12];
    const float* b_out = (const float*)d_in[13];

    char* ws = (char*)d_ws;
    float*  preT      = (float*)ws;                         // 512 KB
    __bf16* WhhB      = (__bf16*)(ws + 524288);             // 256 KB
    __bf16* Wpad      = (__bf16*)(ws + 524288 + 262144);    // 576 KB
    __bf16* char_feat = (__bf16*)(ws + 524288 + 262144 + 589824);  // 4 MB

    prep_kernel<<<256 + (OUTD * KPAD + 2 * G4 * HID + 255) / 256, 256, 0, stream>>>(
        char_table, Wih_f, bih_f, bhh_f, Wih_b, bih_b, bhh_b,
        W_out, Whh_f, Whh_b, preT, Wpad, WhhB);
    lstm_kernel<<<dim3(N_WORDS / WBL, 2), 512, 0, stream>>>(char_ids, preT, WhhB, char_feat);
    out_kernel<<<N_WORDS / WBO, 1024, 0, stream>>>(word_ids, word_table, char_feat, Wpad, b_out,
                                                   (float*)d_out);
}

// Round 5
// 187.443 us; speedup vs baseline: 1.0935x; 1.0568x over previous
//
#include <hip/hip_runtime.h>
#include <hip/hip_bf16.h>

typedef __bf16 bf16x8 __attribute__((ext_vector_type(8)));
typedef float  f32x4  __attribute__((ext_vector_type(4)));
typedef int    i32x4  __attribute__((ext_vector_type(4)));

#define N_WORDS   8192
#define CHAR_LEN  16
#define WORD_DIM  300
#define CHAR_DIM  64
#define HID       128
#define G4        512      // 4*HID
#define INFO      556
#define KPAD      576      // 556 padded to 18*32
#define OUTD      512
#define WBL       16       // words per lstm block (one M16 tile)
#define WBO       32       // words per out block
#define L2E       1.4426950408889634f

// tanh for the output kernel: 1 - 2*rcp(1+exp2(2x*log2e))
__device__ __forceinline__ float tanh_(float x) {
    return 1.0f - 2.0f * __builtin_amdgcn_rcpf(1.0f + __builtin_amdgcn_exp2f((2.0f * L2E) * x));
}

// K0 fused: blocks [0,256): preT ; blocks [256,...): WpadT + WhhB conversion.
// Gate rows prescaled so MFMA output is exp2-ready:
//   rows i,f,o  -> * (-log2e)      => acc = -L2E*gate, sigma = rcp(1+2^acc)
//   rows g      -> * (-2*log2e)    => acc = -2*L2E*g,  tanh = (1-2^acc)/(1+2^acc)
// WpadT layout (coalesced B for out_kernel):
//   WpadT[(((kb*32+g)*4+quad)*16+c16)*8+e] = Wpad_rowmajor[n=g*16+c16][k=kb*32+quad*8+e]
//   -> lane l=quad*16+col loads 16B at offset l*16 within each (kb,g) 1KB panel.
__global__ void prep_kernel(const float* __restrict__ char_table,
                            const float* __restrict__ Wih_f, const float* __restrict__ bih_f,
                            const float* __restrict__ bhh_f,
                            const float* __restrict__ Wih_b, const float* __restrict__ bih_b,
                            const float* __restrict__ bhh_b,
                            const float* __restrict__ W_out,
                            const float* __restrict__ Whh_f, const float* __restrict__ Whh_b,
                            float* __restrict__ preT,
                            __bf16* __restrict__ WpadT, __bf16* __restrict__ WhhB) {
    __shared__ float x[CHAR_DIM];
    if (blockIdx.x < 256) {
        const int dir = blockIdx.x & 1;
        const int cid = blockIdx.x >> 1;
        const float* Wih = dir ? Wih_b : Wih_f;
        const float* b1  = dir ? bih_b : bih_f;
        const float* b2  = dir ? bhh_b : bhh_f;
        if (threadIdx.x < CHAR_DIM) x[threadIdx.x] = char_table[cid * CHAR_DIM + threadIdx.x];
        __syncthreads();
        for (int g = threadIdx.x; g < G4; g += 256) {
            const f32x4* w4 = (const f32x4*)(Wih + g * CHAR_DIM);
            const f32x4* x4 = (const f32x4*)x;
            float s = b1[g] + b2[g];
            #pragma unroll
            for (int d = 0; d < CHAR_DIM / 4; ++d) {
                f32x4 wv = w4[d], xv = x4[d];
                s += wv[0]*xv[0] + wv[1]*xv[1] + wv[2]*xv[2] + wv[3]*xv[3];
            }
            int tt = g >> 7, j = g & (HID - 1);
            float sc = (tt == 2) ? (-2.0f * L2E) : (-L2E);
            preT[(dir * 128 + cid) * G4 + j * 4 + tt] = s * sc;
        }
    } else {
        int idx = (blockIdx.x - 256) * 256 + threadIdx.x;
        if (idx < OUTD * KPAD) {
            int row = idx / KPAD, col = idx - row * KPAD;   // n=row, k=col
            float v = (col < INFO) ? W_out[row * INFO + col] : 0.0f;
            int kb = col >> 5, qd = (col >> 3) & 3, e = col & 7;
            int g = row >> 4, c16 = row & 15;
            int dst = (((((kb << 5) | g) << 2) | qd) << 7) | (c16 << 3) | e;
            WpadT[dst] = (__bf16)v;
        } else {
            int j = idx - OUTD * KPAD;
            if (j < 2 * G4 * HID) {
                const float* src = (j < G4 * HID) ? Whh_f : Whh_b;
                int k = (j < G4 * HID) ? j : j - G4 * HID;
                int gate = (k >> 14) & 3;   // row = k>>7, gate = row>>7
                float sc = (gate == 2) ? (-2.0f * L2E) : (-L2E);
                WhhB[j] = (__bf16)(src[k] * sc);
            }
        }
    }
}

// K2: persistent BiLSTM recurrence.
// Block: 16 words x 1 dir, 512 thr = 8 waves; wave = 16-j slice x M16 words.
// Fully unrolled t-loop; uniform-base 32-bit pref addressing (saddr loads).
__global__ __launch_bounds__(512, 4) void lstm_kernel(
        const int*   __restrict__ char_ids,
        const float* __restrict__ preT,       // [2][128][128][4] fp32 gate-interleaved, prescaled
        const __bf16* __restrict__ WhhB,      // [2][512][128] bf16, prescaled
        __bf16* __restrict__ char_feat) {     // [8192][256] bf16
    const int dir = blockIdx.y;
    const int wb  = blockIdx.x * WBL;
    const __bf16* Whh = WhhB + dir * G4 * HID;
    const float* preD = preT + dir * 128 * G4;

    const int tid  = threadIdx.x;
    const int wave = tid >> 6;
    const int lane = tid & 63;
    const int col  = lane & 15;
    const int quad = lane >> 4;
    const int jbase = wave * 16;

    __shared__ __bf16 h_lds[2][WBL][136];   // [buf][word][j]
    __shared__ int    cidT[CHAR_LEN][WBL];

    if (tid < CHAR_LEN * WBL) {
        int w = tid >> 4, t = tid & 15;
        cidT[t][w] = char_ids[(wb + w) * CHAR_LEN + t] * (G4 * 4);
    }

    bf16x8 Bfrag[4][4];
    #pragma unroll
    for (int tt = 0; tt < 4; ++tt) {
        int row = tt * HID + jbase + col;
        #pragma unroll
        for (int ks = 0; ks < 4; ++ks)
            Bfrag[tt][ks] = *(const bf16x8*)(Whh + row * HID + ks * 32 + quad * 8);
    }

    const int jc16 = (jbase + col) << 4;   // byte offset of this lane's j within a char row

    f32x4 nx[4], acc[4];
    float c[4] = {}, s[4] = {};

    // gather pre-activations for step t: uniform base (preD) + 32-bit lane offset
    auto pref = [&](int t) {
        const int tc = dir ? (CHAR_LEN - 1 - t) : t;
        i32x4 off = *(const i32x4*)(&cidT[tc][quad * 4]);
        #pragma unroll
        for (int r = 0; r < 4; ++r)
            nx[r] = *(const f32x4*)((const char*)preD + (unsigned)(off[r] + jc16));
    };
    auto accinit = [&]() {
        #pragma unroll
        for (int tt = 0; tt < 4; ++tt)
            acc[tt] = (f32x4){nx[0][tt], nx[1][tt], nx[2][tt], nx[3][tt]};
    };
    // acc += Whh . h(t-1)  (h from LDS buffer `buf`)
    auto mfmag = [&](int buf) {
        const __bf16 (*hc)[136] = h_lds[buf];
        #pragma unroll
        for (int ks = 0; ks < 4; ++ks) {
            bf16x8 A = *(const bf16x8*)(&hc[col][ks * 32 + quad * 8]);
            #pragma unroll
            for (int tt = 0; tt < 4; ++tt)
                acc[tt] = __builtin_amdgcn_mfma_f32_16x16x32_bf16(A, Bfrag[tt][ks], acc[tt], 0, 0, 0);
        }
    };
    // Gate math. acc_i/f/o = -L2E*gate, acc_g = -2*L2E*g (prescaled weights).
    //   sigma(x)         = rcp(1 + 2^acc)
    //   sigma(i)*tanh(g) = (1-u) * rcp((1+t)*(1+u))
    //   sigma(o)*tanh(c) = (1-w) * rcp((1+v)*(1+w)),  w=2^(-2*L2E*c)
    // rcp(inf)=0 gives the correct limit; NaN path cut by clamping acc_g at +38.
    auto gates = [&](int buf, bool wr) {
        __bf16 (*hn)[136] = h_lds[buf];
        #pragma unroll
        for (int r = 0; r < 4; ++r) {
            float ti = __builtin_amdgcn_exp2f(acc[0][r]);
            float tf = __builtin_amdgcn_exp2f(acc[1][r]);
            float tg = __builtin_amdgcn_exp2f(fminf(acc[2][r], 38.0f));
            float to = __builtin_amdgcn_exp2f(acc[3][r]);
            float sf = __builtin_amdgcn_rcpf(1.0f + tf);
            float ig = (1.0f - tg) * __builtin_amdgcn_rcpf((1.0f + ti) * (1.0f + tg));
            float cv = sf * c[r] + ig;
            c[r] = cv;
            float tc2 = __builtin_amdgcn_exp2f(cv * (-2.0f * L2E));
            float hv = (1.0f - tc2) * __builtin_amdgcn_rcpf((1.0f + to) * (1.0f + tc2));
            s[r] += hv;
            if (wr) hn[quad * 4 + r][jbase + col] = (__bf16)hv;
        }
    };

    __syncthreads();   // cidT visible

    // t = 0: h(-1) = 0 -> no MFMA.
    pref(0);
    accinit();
    pref(1);
    gates(0, true);            // h(0) -> buf 0
    __syncthreads();

    // t = 1..14, fully unrolled (cross-step scheduling; pref can hoist over barriers).
    #pragma unroll
    for (int tb = 1; tb < CHAR_LEN - 1; tb += 2) {
        // odd t: read buf 0, write buf 1
        accinit();
        pref(tb + 1);
        mfmag(0);
        gates(1, true);
        __syncthreads();
        // even t: read buf 1, write buf 0
        accinit();
        pref(tb + 2);
        mfmag(1);
        gates(0, true);
        __syncthreads();
    }

    // t = 15: read buf 0, no write.
    accinit();
    mfmag(0);
    gates(1, false);

    #pragma unroll
    for (int r = 0; r < 4; ++r)
        char_feat[(wb + quad * 4 + r) * 256 + dir * HID + jbase + col] = (__bf16)s[r];
}

// K3: 1024 thr (16 waves), M=32 words/block, wave owns M32 x N32 tile.
// launch_bounds(1024,2): 128-VGPR cap (the old (1024,4)=64 likely spilled).
// B loads now fully coalesced from WpadT (wave reads contiguous 1KB panels).
__global__ __launch_bounds__(1024, 2) void out_kernel(
        const int*   __restrict__ word_ids,
        const float* __restrict__ word_table,   // [50000][300] fp32
        const __bf16* __restrict__ char_feat,   // [8192][256] bf16
        const __bf16* __restrict__ WpadT,       // transposed [18][32][4][16][8] bf16
        const float* __restrict__ b_out,        // [512] fp32
        float* __restrict__ out) {              // [8192][512] fp32
    const int wb  = blockIdx.x * WBO;
    const int tid = threadIdx.x;
    const int wave = tid >> 6, lane = tid & 63, col = lane & 15, quad = lane >> 4;
    const int nbase = wave * 32;   // 16 waves x 32 = 512 outputs

    __shared__ __bf16 feat[WBO][584];   // 1168B row stride, 16B aligned
    __shared__ int wid[WBO];
    if (tid < WBO) wid[tid] = word_ids[wb + tid];
    __syncthreads();
    // word part: 32 rows x 75 f32x4 chunks
    for (int idx = tid; idx < WBO * 75; idx += 1024) {
        int row = idx / 75, ch = idx - row * 75;
        f32x4 v = *(const f32x4*)(word_table + wid[row] * WORD_DIM + ch * 4);
        __bf16* d = &feat[row][ch * 4];
        d[0] = (__bf16)v[0]; d[1] = (__bf16)v[1]; d[2] = (__bf16)v[2]; d[3] = (__bf16)v[3];
    }
    // char part: 32 rows x 32 bf16x8 chunks = 1024 exactly
    {
        int row = tid >> 5, ch = tid & 31;
        bf16x8 v = *(const bf16x8*)(char_feat + (wb + row) * 256 + ch * 8);
        __bf16* d = &feat[row][WORD_DIM + ch * 8];
        #pragma unroll
        for (int e = 0; e < 8; ++e) d[e] = v[e];
    }
    // zero pad 556..583 : 32 x 28 = 896
    if (tid < WBO * 28) {
        int row = tid / 28, cc = tid - row * 28;
        feat[row][INFO + cc] = (__bf16)0.0f;
    }
    __syncthreads();

    f32x4 acc[2][2];   // [mt][nt]
    #pragma unroll
    for (int mt = 0; mt < 2; ++mt)
        #pragma unroll
        for (int nt = 0; nt < 2; ++nt) acc[mt][nt] = (f32x4){0.f, 0.f, 0.f, 0.f};

    // B0: n-group g0=wave*2 -> WpadT + ((g0*4+quad)*16+col)*8 = +(wave*8+quad)*128+col*8
    // B1: g1=g0+1 -> +512 elements. Per-kb stride = 32*4*16*8 = 16384 elements.
    const __bf16* bpT = WpadT + (wave * 8 + quad) * 128 + col * 8;

    #pragma unroll 2
    for (int kb = 0; kb < KPAD / 32; ++kb) {
        const int kbo = kb * 16384;
        bf16x8 B0 = *(const bf16x8*)(bpT + kbo);
        bf16x8 B1 = *(const bf16x8*)(bpT + kbo + 512);
        const int ko = kb * 32 + quad * 8;
        bf16x8 A0 = *(const bf16x8*)(&feat[col][ko]);
        bf16x8 A1 = *(const bf16x8*)(&feat[16 + col][ko]);
        acc[0][0] = __builtin_amdgcn_mfma_f32_16x16x32_bf16(A0, B0, acc[0][0], 0, 0, 0);
        acc[1][0] = __builtin_amdgcn_mfma_f32_16x16x32_bf16(A1, B0, acc[1][0], 0, 0, 0);
        acc[0][1] = __builtin_amdgcn_mfma_f32_16x16x32_bf16(A0, B1, acc[0][1], 0, 0, 0);
        acc[1][1] = __builtin_amdgcn_mfma_f32_16x16x32_bf16(A1, B1, acc[1][1], 0, 0, 0);
    }

    #pragma unroll
    for (int nt = 0; nt < 2; ++nt) {
        int n = nbase + nt * 16 + col;
        float bo = b_out[n];
        #pragma unroll
        for (int mt = 0; mt < 2; ++mt)
            #pragma unroll
            for (int r = 0; r < 4; ++r) {
                int word = wb + mt * 16 + quad * 4 + r;
                out[word * OUTD + n] = tanh_(acc[mt][nt][r] + bo);
            }
    }
}

extern "C" void kernel_launch(void* const* d_in, const int* in_sizes, int n_in,
                              void* d_out, int out_size, void* d_ws, size_t ws_size,
                              hipStream_t stream) {
    const int*   word_ids   = (const int*)d_in[0];
    const int*   char_ids   = (const int*)d_in[1];
    const float* word_table = (const float*)d_in[2];
    const float* char_table = (const float*)d_in[3];
    const float* Wih_f = (const float*)d_in[4];
    const float* Whh_f = (const float*)d_in[5];
    const float* bih_f = (const float*)d_in[6];
    const float* bhh_f = (const float*)d_in[7];
    const float* Wih_b = (const float*)d_in[8];
    const float* Whh_b = (const float*)d_in[9];
    const float* bih_b = (const float*)d_in[10];
    const float* bhh_b = (const float*)d_in[11];
    const float* W_out = (const float*)d_in[12];
    const float* b_out = (const float*)d_in[13];

    char* ws = (char*)d_ws;
    float*  preT      = (float*)ws;                         // 512 KB
    __bf16* WhhB      = (__bf16*)(ws + 524288);             // 256 KB
    __bf16* WpadT     = (__bf16*)(ws + 524288 + 262144);    // 576 KB
    __bf16* char_feat = (__bf16*)(ws + 524288 + 262144 + 589824);  // 4 MB

    prep_kernel<<<256 + (OUTD * KPAD + 2 * G4 * HID + 255) / 256, 256, 0, stream>>>(
        char_table, Wih_f, bih_f, bhh_f, Wih_b, bih_b, bhh_b,
        W_out, Whh_f, Whh_b, preT, WpadT, WhhB);
    lstm_kernel<<<dim3(N_WORDS / WBL, 2), 512, 0, stream>>>(char_ids, preT, WhhB, char_feat);
    out_kernel<<<N_WORDS / WBO, 1024, 0, stream>>>(word_ids, word_table, char_feat, WpadT, b_out,
                                                   (float*)d_out);
}

// Round 6
// 186.456 us; speedup vs baseline: 1.0992x; 1.0053x over previous
//
#include <hip/hip_runtime.h>
#include <hip/hip_bf16.h>

typedef __bf16 bf16x8 __attribute__((ext_vector_type(8)));
typedef float  f32x4  __attribute__((ext_vector_type(4)));
typedef int    i32x4  __attribute__((ext_vector_type(4)));

#define N_WORDS   8192
#define CHAR_LEN  16
#define WORD_DIM  300
#define CHAR_DIM  64
#define HID       128
#define G4        512      // 4*HID
#define INFO      556
#define KPAD      576      // 556 padded to 18*32
#define OUTD      512
#define WBL       16       // words per lstm block (one M16 tile)
#define WBO       32       // words per out block
#define L2E       1.4426950408889634f

// tanh for the output kernel: 1 - 2*rcp(1+exp2(2x*log2e))
__device__ __forceinline__ float tanh_(float x) {
    return 1.0f - 2.0f * __builtin_amdgcn_rcpf(1.0f + __builtin_amdgcn_exp2f((2.0f * L2E) * x));
}

// K0 fused: blocks [0,256): preT ; blocks [256,...): WpadT + WhhB conversion.
// Gate rows prescaled so MFMA output is exp2-ready:
//   rows i,f,o  -> * (-log2e)      => acc = -L2E*gate, sigma = rcp(1+2^acc)
//   rows g      -> * (-2*log2e)    => acc = -2*L2E*g,  tanh = (1-2^acc)/(1+2^acc)
// WpadT layout (coalesced B for out_kernel):
//   WpadT[(((kb*32+g)*4+quad)*16+c16)*8+e] = Wpad_rowmajor[n=g*16+c16][k=kb*32+quad*8+e]
//   -> lane l=quad*16+col loads 16B at offset l*16 within each (kb,g) 1KB panel.
__global__ void prep_kernel(const float* __restrict__ char_table,
                            const float* __restrict__ Wih_f, const float* __restrict__ bih_f,
                            const float* __restrict__ bhh_f,
                            const float* __restrict__ Wih_b, const float* __restrict__ bih_b,
                            const float* __restrict__ bhh_b,
                            const float* __restrict__ W_out,
                            const float* __restrict__ Whh_f, const float* __restrict__ Whh_b,
                            float* __restrict__ preT,
                            __bf16* __restrict__ WpadT, __bf16* __restrict__ WhhB) {
    __shared__ float x[CHAR_DIM];
    if (blockIdx.x < 256) {
        const int dir = blockIdx.x & 1;
        const int cid = blockIdx.x >> 1;
        const float* Wih = dir ? Wih_b : Wih_f;
        const float* b1  = dir ? bih_b : bih_f;
        const float* b2  = dir ? bhh_b : bhh_f;
        if (threadIdx.x < CHAR_DIM) x[threadIdx.x] = char_table[cid * CHAR_DIM + threadIdx.x];
        __syncthreads();
        for (int g = threadIdx.x; g < G4; g += 256) {
            const f32x4* w4 = (const f32x4*)(Wih + g * CHAR_DIM);
            const f32x4* x4 = (const f32x4*)x;
            float s = b1[g] + b2[g];
            #pragma unroll
            for (int d = 0; d < CHAR_DIM / 4; ++d) {
                f32x4 wv = w4[d], xv = x4[d];
                s += wv[0]*xv[0] + wv[1]*xv[1] + wv[2]*xv[2] + wv[3]*xv[3];
            }
            int tt = g >> 7, j = g & (HID - 1);
            float sc = (tt == 2) ? (-2.0f * L2E) : (-L2E);
            preT[(dir * 128 + cid) * G4 + j * 4 + tt] = s * sc;
        }
    } else {
        int idx = (blockIdx.x - 256) * 256 + threadIdx.x;
        if (idx < OUTD * KPAD) {
            int row = idx / KPAD, col = idx - row * KPAD;   // n=row, k=col
            float v = (col < INFO) ? W_out[row * INFO + col] : 0.0f;
            int kb = col >> 5, qd = (col >> 3) & 3, e = col & 7;
            int g = row >> 4, c16 = row & 15;
            int dst = (((((kb << 5) | g) << 2) | qd) << 7) | (c16 << 3) | e;
            WpadT[dst] = (__bf16)v;
        } else {
            int j = idx - OUTD * KPAD;
            if (j < 2 * G4 * HID) {
                const float* src = (j < G4 * HID) ? Whh_f : Whh_b;
                int k = (j < G4 * HID) ? j : j - G4 * HID;
                int gate = (k >> 14) & 3;   // row = k>>7, gate = row>>7
                float sc = (gate == 2) ? (-2.0f * L2E) : (-L2E);
                WhhB[j] = (__bf16)(src[k] * sc);
            }
        }
    }
}

// K2: persistent BiLSTM recurrence (R4-proven form: compact 2-step loop body).
// Block: 16 words x 1 dir, 512 thr = 8 waves; wave = 16-j slice x M16 words.
__global__ __launch_bounds__(512, 4) void lstm_kernel(
        const int*   __restrict__ char_ids,
        const float* __restrict__ preT,       // [2][128][128][4] fp32 gate-interleaved, prescaled
        const __bf16* __restrict__ WhhB,      // [2][512][128] bf16, prescaled
        __bf16* __restrict__ char_feat) {     // [8192][256] bf16
    const int dir = blockIdx.y;
    const int wb  = blockIdx.x * WBL;
    const __bf16* Whh = WhhB + dir * G4 * HID;
    const float* preD = preT + dir * 128 * G4;

    const int tid  = threadIdx.x;
    const int wave = tid >> 6;
    const int lane = tid & 63;
    const int col  = lane & 15;
    const int quad = lane >> 4;
    const int jbase = wave * 16;

    __shared__ __bf16 h_lds[2][WBL][136];   // [buf][word][j]
    __shared__ int    cidT[CHAR_LEN][WBL];

    if (tid < CHAR_LEN * WBL) {
        int w = tid >> 4, t = tid & 15;
        cidT[t][w] = char_ids[(wb + w) * CHAR_LEN + t] * (G4 * 4);
    }

    bf16x8 Bfrag[4][4];
    #pragma unroll
    for (int tt = 0; tt < 4; ++tt) {
        int row = tt * HID + jbase + col;
        #pragma unroll
        for (int ks = 0; ks < 4; ++ks)
            Bfrag[tt][ks] = *(const bf16x8*)(Whh + row * HID + ks * 32 + quad * 8);
    }

    const char* base_lane = (const char*)(preD + (jbase + col) * 4);

    f32x4 nx[4], acc[4];
    float c[4] = {}, s[4] = {};

    // gather pre-activations for step t (4 words per lane, 16B each)
    auto pref = [&](int t) {
        const int tc = dir ? (CHAR_LEN - 1 - t) : t;
        i32x4 off = *(const i32x4*)(&cidT[tc][quad * 4]);
        #pragma unroll
        for (int r = 0; r < 4; ++r)
            nx[r] = *(const f32x4*)(base_lane + off[r]);
    };
    auto accinit = [&]() {
        #pragma unroll
        for (int tt = 0; tt < 4; ++tt)
            acc[tt] = (f32x4){nx[0][tt], nx[1][tt], nx[2][tt], nx[3][tt]};
    };
    // acc += Whh . h(t-1)  (h from LDS buffer `buf`)
    auto mfmag = [&](int buf) {
        const __bf16 (*hc)[136] = h_lds[buf];
        #pragma unroll
        for (int ks = 0; ks < 4; ++ks) {
            bf16x8 A = *(const bf16x8*)(&hc[col][ks * 32 + quad * 8]);
            #pragma unroll
            for (int tt = 0; tt < 4; ++tt)
                acc[tt] = __builtin_amdgcn_mfma_f32_16x16x32_bf16(A, Bfrag[tt][ks], acc[tt], 0, 0, 0);
        }
    };
    // Gate math. acc_i/f/o = -L2E*gate, acc_g = -2*L2E*g (prescaled weights).
    //   sigma(x)         = rcp(1 + 2^acc)
    //   sigma(i)*tanh(g) = (1-u) * rcp((1+t)*(1+u))
    //   sigma(o)*tanh(c) = (1-w) * rcp((1+v)*(1+w)),  w=2^(-2*L2E*c)
    // rcp(inf)=0 gives the correct limit; NaN path cut by clamping acc_g at +38.
    auto gates = [&](int buf, bool wr) {
        __bf16 (*hn)[136] = h_lds[buf];
        #pragma unroll
        for (int r = 0; r < 4; ++r) {
            float ti = __builtin_amdgcn_exp2f(acc[0][r]);
            float tf = __builtin_amdgcn_exp2f(acc[1][r]);
            float tg = __builtin_amdgcn_exp2f(fminf(acc[2][r], 38.0f));
            float to = __builtin_amdgcn_exp2f(acc[3][r]);
            float sf = __builtin_amdgcn_rcpf(1.0f + tf);
            float ig = (1.0f - tg) * __builtin_amdgcn_rcpf((1.0f + ti) * (1.0f + tg));
            float cv = sf * c[r] + ig;
            c[r] = cv;
            float tc2 = __builtin_amdgcn_exp2f(cv * (-2.0f * L2E));
            float hv = (1.0f - tc2) * __builtin_amdgcn_rcpf((1.0f + to) * (1.0f + tc2));
            s[r] += hv;
            if (wr) hn[quad * 4 + r][jbase + col] = (__bf16)hv;
        }
    };

    __syncthreads();   // cidT visible

    // t = 0: h(-1) = 0 -> no MFMA.
    pref(0);
    accinit();
    pref(1);
    gates(0, true);            // h(0) -> buf 0
    __syncthreads();

    // t = 1..14, 2x unrolled for static buffer indices (compact body; NOT fully
    // unrolled — R5 showed full unroll regresses ~5%, likely i-cache).
    #pragma unroll 1
    for (int tb = 1; tb < CHAR_LEN - 1; tb += 2) {
        // odd t: read buf 0, write buf 1
        accinit();
        pref(tb + 1);
        mfmag(0);
        gates(1, true);
        __syncthreads();
        // even t: read buf 1, write buf 0
        accinit();
        pref(tb + 2);
        mfmag(1);
        gates(0, true);
        __syncthreads();
    }

    // t = 15: read buf 0, no write.
    accinit();
    mfmag(0);
    gates(1, false);

    #pragma unroll
    for (int r = 0; r < 4; ++r)
        char_feat[(wb + quad * 4 + r) * 256 + dir * HID + jbase + col] = (__bf16)s[r];
}

// K3: 1024 thr (16 waves), M=32 words/block, wave owns M32 x N32 tile.
// launch_bounds(1024,2): 128-VGPR cap (old (1024,4)=64 spilled).
// B loads fully coalesced from WpadT (wave reads contiguous 1KB panels).
__global__ __launch_bounds__(1024, 2) void out_kernel(
        const int*   __restrict__ word_ids,
        const float* __restrict__ word_table,   // [50000][300] fp32
        const __bf16* __restrict__ char_feat,   // [8192][256] bf16
        const __bf16* __restrict__ WpadT,       // transposed [18][32][4][16][8] bf16
        const float* __restrict__ b_out,        // [512] fp32
        float* __restrict__ out) {              // [8192][512] fp32
    const int wb  = blockIdx.x * WBO;
    const int tid = threadIdx.x;
    const int wave = tid >> 6, lane = tid & 63, col = lane & 15, quad = lane >> 4;
    const int nbase = wave * 32;   // 16 waves x 32 = 512 outputs

    __shared__ __bf16 feat[WBO][584];   // 1168B row stride, 16B aligned
    __shared__ int wid[WBO];
    if (tid < WBO) wid[tid] = word_ids[wb + tid];
    __syncthreads();
    // word part: 32 rows x 75 f32x4 chunks
    for (int idx = tid; idx < WBO * 75; idx += 1024) {
        int row = idx / 75, ch = idx - row * 75;
        f32x4 v = *(const f32x4*)(word_table + wid[row] * WORD_DIM + ch * 4);
        __bf16* d = &feat[row][ch * 4];
        d[0] = (__bf16)v[0]; d[1] = (__bf16)v[1]; d[2] = (__bf16)v[2]; d[3] = (__bf16)v[3];
    }
    // char part: 32 rows x 32 bf16x8 chunks = 1024 exactly
    {
        int row = tid >> 5, ch = tid & 31;
        bf16x8 v = *(const bf16x8*)(char_feat + (wb + row) * 256 + ch * 8);
        __bf16* d = &feat[row][WORD_DIM + ch * 8];
        #pragma unroll
        for (int e = 0; e < 8; ++e) d[e] = v[e];
    }
    // zero pad 556..583 : 32 x 28 = 896
    if (tid < WBO * 28) {
        int row = tid / 28, cc = tid - row * 28;
        feat[row][INFO + cc] = (__bf16)0.0f;
    }
    __syncthreads();

    f32x4 acc[2][2];   // [mt][nt]
    #pragma unroll
    for (int mt = 0; mt < 2; ++mt)
        #pragma unroll
        for (int nt = 0; nt < 2; ++nt) acc[mt][nt] = (f32x4){0.f, 0.f, 0.f, 0.f};

    // B0: n-group g0=wave*2 -> WpadT + ((g0*4+quad)*16+col)*8 = +(wave*8+quad)*128+col*8
    // B1: g1=g0+1 -> +512 elements. Per-kb stride = 32*4*16*8 = 16384 elements.
    const __bf16* bpT = WpadT + (wave * 8 + quad) * 128 + col * 8;

    #pragma unroll 2
    for (int kb = 0; kb < KPAD / 32; ++kb) {
        const int kbo = kb * 16384;
        bf16x8 B0 = *(const bf16x8*)(bpT + kbo);
        bf16x8 B1 = *(const bf16x8*)(bpT + kbo + 512);
        const int ko = kb * 32 + quad * 8;
        bf16x8 A0 = *(const bf16x8*)(&feat[col][ko]);
        bf16x8 A1 = *(const bf16x8*)(&feat[16 + col][ko]);
        acc[0][0] = __builtin_amdgcn_mfma_f32_16x16x32_bf16(A0, B0, acc[0][0], 0, 0, 0);
        acc[1][0] = __builtin_amdgcn_mfma_f32_16x16x32_bf16(A1, B0, acc[1][0], 0, 0, 0);
        acc[0][1] = __builtin_amdgcn_mfma_f32_16x16x32_bf16(A0, B1, acc[0][1], 0, 0, 0);
        acc[1][1] = __builtin_amdgcn_mfma_f32_16x16x32_bf16(A1, B1, acc[1][1], 0, 0, 0);
    }

    #pragma unroll
    for (int nt = 0; nt < 2; ++nt) {
        int n = nbase + nt * 16 + col;
        float bo = b_out[n];
        #pragma unroll
        for (int mt = 0; mt < 2; ++mt)
            #pragma unroll
            for (int r = 0; r < 4; ++r) {
                int word = wb + mt * 16 + quad * 4 + r;
                out[word * OUTD + n] = tanh_(acc[mt][nt][r] + bo);
            }
    }
}

extern "C" void kernel_launch(void* const* d_in, const int* in_sizes, int n_in,
                              void* d_out, int out_size, void* d_ws, size_t ws_size,
                              hipStream_t stream) {
    const int*   word_ids   = (const int*)d_in[0];
    const int*   char_ids   = (const int*)d_in[1];
    const float* word_table = (const float*)d_in[2];
    const float* char_table = (const float*)d_in[3];
    const float* Wih_f = (const float*)d_in[4];
    const float* Whh_f = (const float*)d_in[5];
    const float* bih_f = (const float*)d_in[6];
    const float* bhh_f = (const float*)d_in[7];
    const float* Wih_b = (const float*)d_in[8];
    const float* Whh_b = (const float*)d_in[9];
    const float* bih_b = (const float*)d_in[10];
    const float* bhh_b = (const float*)d_in[11];
    const float* W_out = (const float*)d_in[12];
    const float* b_out = (const float*)d_in[13];

    char* ws = (char*)d_ws;
    float*  preT      = (float*)ws;                         // 512 KB
    __bf16* WhhB      = (__bf16*)(ws + 524288);             // 256 KB
    __bf16* WpadT     = (__bf16*)(ws + 524288 + 262144);    // 576 KB
    __bf16* char_feat = (__bf16*)(ws + 524288 + 262144 + 589824);  // 4 MB

    prep_kernel<<<256 + (OUTD * KPAD + 2 * G4 * HID + 255) / 256, 256, 0, stream>>>(
        char_table, Wih_f, bih_f, bhh_f, Wih_b, bih_b, bhh_b,
        W_out, Whh_f, Whh_b, preT, WpadT, WhhB);
    lstm_kernel<<<dim3(N_WORDS / WBL, 2), 512, 0, stream>>>(char_ids, preT, WhhB, char_feat);
    out_kernel<<<N_WORDS / WBO, 1024, 0, stream>>>(word_ids, word_table, char_feat, WpadT, b_out,
                                                   (float*)d_out);
}